// Round 17
// baseline (1016.728 us; speedup 1.0000x reference)
//
#include <hip/hip_runtime.h>

#define BB 1024
#define TT 200

typedef __attribute__((ext_vector_type(8))) short short8;
typedef __attribute__((ext_vector_type(2))) short short2v;
typedef __attribute__((ext_vector_type(4))) float f32x4;
typedef __attribute__((ext_vector_type(4))) unsigned uint4v;

__device__ __forceinline__ float sigmoidf_(float x) { return __fdividef(1.0f, 1.0f + __expf(-x)); }
__device__ __forceinline__ float tanh_fast(float x) {
    x = fminf(15.f, fmaxf(-15.f, x));
    float e = __expf(-2.f * x);
    return __fdividef(1.f - e, 1.f + e);
}
__device__ __forceinline__ float dicef_(float x, float m, float v) {
    return x * sigmoidf_((x - m) * rsqrtf(v + 1e-9f));
}
__device__ __forceinline__ unsigned short f2bf(float f) {
    unsigned u = __float_as_uint(f);
    unsigned r = u + 0x7fffu + ((u >> 16) & 1u);
    return (unsigned short)(r >> 16);
}
__device__ __forceinline__ float bf2f(unsigned short h) {
    return __uint_as_float(((unsigned)h) << 16);
}
__device__ __forceinline__ unsigned cvt_pk_bf16(float lo, float hi) {
    unsigned r;
    asm("v_cvt_pk_bf16_f32 %0, %1, %2" : "=v"(r) : "v"(lo), "v"(hi));
    return r;
}
union U8 { short8 s8; unsigned u[4]; };
union UU { short8 s8v; uint4v u4; uint2 u2[2]; };

// ---------------------------------------------------------------------------
// k_prep
// ---------------------------------------------------------------------------
__global__ void k_prep(const float* __restrict__ dense, const int* __restrict__ sparse,
                       const int* __restrict__ item_idx, const float* __restrict__ table,
                       const float* __restrict__ other_tables,
                       float* __restrict__ target, float* __restrict__ other) {
    int b = blockIdx.x, l = threadIdx.x;  // 64 threads
    target[b * 64 + l] = table[(size_t)item_idx[b] * 64 + l];
    if (l < 4) other[b * 36 + l] = dense[b * 4 + l];
    else if (l < 20) other[b * 36 + l] = other_tables[(size_t)sparse[b * 2 + 0] * 16 + (l - 4)];
    else if (l < 36) other[b * 36 + l] = other_tables[1000 * 16 + (size_t)sparse[b * 2 + 1] * 16 + (l - 20)];
}

// ---------------------------------------------------------------------------
// k_scanM: FUSED xw + recurrence MFMA scan. ONE WAVE per 16 batch rows,
// ZERO barriers (single-wave lockstep; in-order per-wave DS pipe).
// Per step t:  G^T = U^T(192x64) h^T(64x16)  +  W^T(192x64) x_t^T(64x16)
// via 48 x mfma_f32_16x16x32_bf16 (12 m-tiles x 2 K-chunks x {U,W}).
// hh keeps x- and h-parts in SEPARATE accumulators (r gates only hU).
// Layouts are r5's hardware-verified fragment formulas:
//   A-frag (lane lg,li): A[li][k=32c+8lg+j]   (gate-col 16mt+li of U/W)
//   B-frag: B[k=32c+8lg+j][li] = h/x[b_li][k]
//   C-frag: (gate-row 16mt+4lg+jj, batch li)
// Weights live in LDS: per-lane private 48 x 16B slots, XOR-swizzled
// (slot s at (s&~7)|((s&7)^(l&7)) -> 8 lanes/bank-quad, conflict-free).
// h exchange: r5's swizzled hbuf write(4xb64)/read(2xb128), single buffer
// (reads of step t precede writes in program order within the wave).
// Grid = 64 blocks -> <=1 wave/CU -> ZERO LDS pipe contention (the r11-r16
// ~1800cy/step wall was 4 waves/CU x 32 b128 x 12cy sharing one LDS pipe).
// GATHER=1: x = item_table[seq_idx] (fused gather; k_xw deleted).
// AUG=1: z *= scores; writes hfinal. Else writes hout (B,T,64) bf16.
// ---------------------------------------------------------------------------
template <int GATHER, int AUG>
__global__ __launch_bounds__(64, 1) void k_scanM(
    const int* __restrict__ seq_idx,         // (B,T) when GATHER
    const float* __restrict__ table,         // (1M,64) when GATHER
    const unsigned short* __restrict__ xsrc, // (B,T,64) bf16 when !GATHER
    const float* __restrict__ U,             // (64,192)
    const float* __restrict__ W,             // (64,192)
    const float* __restrict__ bias,          // (192)
    const int* __restrict__ hist_len,
    const float* __restrict__ scores,        // (B,T) when AUG
    unsigned short* __restrict__ hout,       // (B,T,64) bf16 (!AUG)
    float* __restrict__ hfinal)              // (B,64) f32 (AUG)
{
    __shared__ unsigned ldsimg[64 * 192];        // 48 KB: 64 lanes x 48 slots x 16B
    __shared__ unsigned short hbuf[16 * 64];     // 2 KB h exchange (swizzled)

    const int l = threadIdx.x, lg = l >> 4, li = l & 15;
    const unsigned s8 = (unsigned)l & 7u;
    const int b = blockIdx.x * 16 + li;
    const int len = hist_len[b];
    int tmax = len;
#pragma unroll
    for (int m = 1; m < 64; m <<= 1) { int o = __shfl_xor(tmax, m); tmax = (o > tmax) ? o : tmax; }

    unsigned* lb = ldsimg + l * 192;
    // ---- stage U^T / W^T A-fragments into per-lane LDS slots (once) ----
    for (int g = 0; g < 3; ++g)
        for (int t4 = 0; t4 < 4; ++t4) {
            const int col = g * 64 + t4 * 16 + li;
            for (int c = 0; c < 2; ++c) {
                UU fu, fw;
#pragma unroll
                for (int j = 0; j < 8; ++j) {
                    int k = c * 32 + lg * 8 + j;
                    fu.s8v[j] = (short)f2bf(U[k * 192 + col]);
                    fw.s8v[j] = (short)f2bf(W[k * 192 + col]);
                }
                const int s = (g * 4 + t4) * 2 + c;       // U slot 0..23
                const int sw_ = 24 + s;                   // W slot 24..47
                ((uint4v*)lb)[(unsigned)(s & ~7) | (((unsigned)s & 7u) ^ s8)] = fu.u4;
                ((uint4v*)lb)[(unsigned)(sw_ & ~7) | (((unsigned)sw_ & 7u) ^ s8)] = fw.u4;
            }
        }

    // biases (per-lane constants; compiler may cache or re-load from L1)
    f32x4 bz[4], br[4], bh[4];
#pragma unroll
    for (int tz = 0; tz < 4; ++tz)
#pragma unroll
        for (int jj = 0; jj < 4; ++jj) {
            int d = 16 * tz + 4 * lg + jj;
            bz[tz][jj] = bias[d];
            br[tz][jj] = bias[64 + d];
            bh[tz][jj] = bias[128 + d];
        }

    // h exchange addresses (r5 pattern)
    char* hbB = (char*)hbuf + li * 128;
#define WBA(tz) ((uint2*)(hbB + ((((tz) * 32 + lg * 8)) ^ (s8 << 4))))
#define RBA(c)  (*(const uint4v*)(hbB + ((((c) * 64 + lg * 16)) ^ (s8 << 4))))
    {
        uint2 z2; z2.x = 0u; z2.y = 0u;
#pragma unroll
        for (int tz = 0; tz < 4; ++tz) *WBA(tz) = z2;
    }

    f32x4 hp[4];
#pragma unroll
    for (int tz = 0; tz < 4; ++tz) hp[tz] = (f32x4){0.f, 0.f, 0.f, 0.f};

#define RDS(s) (((const uint4v*)lb)[(unsigned)((s) & ~7) | (((unsigned)(s) & 7u) ^ s8)])

    // ---- x prefetch state ----
    const int* idxr = GATHER ? (seq_idx + (size_t)b * TT) : nullptr;
    const unsigned short* xr = GATHER ? nullptr : (xsrc + (size_t)b * TT * 64);
    const float* scr = AUG ? (scores + (size_t)b * TT) : nullptr;

    f32x4 ra0 = {}, ra1 = {}, rb0 = {}, rb1 = {};   // GATHER raw f32 (cur)
    uint4v xc0 = {}, xc1 = {};                       // !GATHER bf16 (cur)
    int idn = 0;
    float sc = 0.f;
    if (GATHER) {
        int id0 = idxr[0];
        const float* tp = table + (size_t)id0 * 64;
        ra0 = *(const f32x4*)(tp + 8 * lg);
        ra1 = *(const f32x4*)(tp + 8 * lg + 4);
        rb0 = *(const f32x4*)(tp + 32 + 8 * lg);
        rb1 = *(const f32x4*)(tp + 32 + 8 * lg + 4);
        idn = idxr[1 < TT ? 1 : 0];
    } else {
        xc0 = *(const uint4v*)(xr + 8 * lg);
        xc1 = *(const uint4v*)(xr + 32 + 8 * lg);
    }
    if (AUG) sc = scr[0];

    unsigned short* horB = hout + (size_t)b * TT * 64;

    for (int t = 0; t < tmax; ++t) {
        // ---- issue next-step x loads (latency hidden under this step) ----
        f32x4 na0 = ra0, na1 = ra1, nb0 = rb0, nb1 = rb1;
        uint4v nx0 = xc0, nx1 = xc1;
        int idn2 = idn;
        float ns = sc;
        if (t + 1 < TT) {
            if (GATHER) {
                const float* tp = table + (size_t)idn * 64;
                na0 = *(const f32x4*)(tp + 8 * lg);
                na1 = *(const f32x4*)(tp + 8 * lg + 4);
                nb0 = *(const f32x4*)(tp + 32 + 8 * lg);
                nb1 = *(const f32x4*)(tp + 32 + 8 * lg + 4);
                idn2 = idxr[(t + 2 < TT) ? (t + 2) : (TT - 1)];
            } else {
                const unsigned short* xp = xr + (size_t)(t + 1) * 64;
                nx0 = *(const uint4v*)(xp + 8 * lg);
                nx1 = *(const uint4v*)(xp + 32 + 8 * lg);
            }
            if (AUG) ns = scr[t + 1];
        }

        // ---- build x B-frags ----
        UU xb0, xb1;
        if (GATHER) {
            xb0.u4[0] = cvt_pk_bf16(ra0[0], ra0[1]);
            xb0.u4[1] = cvt_pk_bf16(ra0[2], ra0[3]);
            xb0.u4[2] = cvt_pk_bf16(ra1[0], ra1[1]);
            xb0.u4[3] = cvt_pk_bf16(ra1[2], ra1[3]);
            xb1.u4[0] = cvt_pk_bf16(rb0[0], rb0[1]);
            xb1.u4[1] = cvt_pk_bf16(rb0[2], rb0[3]);
            xb1.u4[2] = cvt_pk_bf16(rb1[0], rb1[1]);
            xb1.u4[3] = cvt_pk_bf16(rb1[2], rb1[3]);
        } else {
            xb0.u4 = xc0;
            xb1.u4 = xc1;
        }

        // ---- h B-frags (written end of previous step; in-order DS pipe) ----
        UU hb0, hb1;
        hb0.u4 = RBA(0);
        hb1.u4 = RBA(1);

        // ---- 48 MFMAs ----
        f32x4 aZR[8];
#pragma unroll
        for (int mt = 0; mt < 8; ++mt) {
            UU A;
            f32x4 acc = (f32x4){0.f, 0.f, 0.f, 0.f};
            A.u4 = RDS(mt * 2);     acc = __builtin_amdgcn_mfma_f32_16x16x32_bf16(A.s8v, hb0.s8v, acc, 0, 0, 0);
            A.u4 = RDS(mt * 2 + 1); acc = __builtin_amdgcn_mfma_f32_16x16x32_bf16(A.s8v, hb1.s8v, acc, 0, 0, 0);
            A.u4 = RDS(24 + mt * 2);     acc = __builtin_amdgcn_mfma_f32_16x16x32_bf16(A.s8v, xb0.s8v, acc, 0, 0, 0);
            A.u4 = RDS(24 + mt * 2 + 1); acc = __builtin_amdgcn_mfma_f32_16x16x32_bf16(A.s8v, xb1.s8v, acc, 0, 0, 0);
            aZR[mt] = acc;
        }
        f32x4 aHU[4], aHX[4];
#pragma unroll
        for (int q = 0; q < 4; ++q) {
            const int mt = 8 + q;
            UU A;
            f32x4 accu = (f32x4){0.f, 0.f, 0.f, 0.f};
            f32x4 accx = (f32x4){0.f, 0.f, 0.f, 0.f};
            A.u4 = RDS(mt * 2);     accu = __builtin_amdgcn_mfma_f32_16x16x32_bf16(A.s8v, hb0.s8v, accu, 0, 0, 0);
            A.u4 = RDS(mt * 2 + 1); accu = __builtin_amdgcn_mfma_f32_16x16x32_bf16(A.s8v, hb1.s8v, accu, 0, 0, 0);
            A.u4 = RDS(24 + mt * 2);     accx = __builtin_amdgcn_mfma_f32_16x16x32_bf16(A.s8v, xb0.s8v, accx, 0, 0, 0);
            A.u4 = RDS(24 + mt * 2 + 1); accx = __builtin_amdgcn_mfma_f32_16x16x32_bf16(A.s8v, xb1.s8v, accx, 0, 0, 0);
            aHU[q] = accu;
            aHX[q] = accx;
        }

        // ---- gates (lane-local, 16 dims) + h exchange + hout ----
        const bool upd = (t < len);
#pragma unroll
        for (int tz = 0; tz < 4; ++tz) {
#pragma unroll
            for (int jj = 0; jj < 4; ++jj) {
                float z = sigmoidf_(aZR[tz][jj] + bz[tz][jj]);
                if (AUG) z *= sc;
                float r = sigmoidf_(aZR[4 + tz][jj] + br[tz][jj]);
                float hh = tanh_fast(aHX[tz][jj] + bh[tz][jj] + r * aHU[tz][jj]);
                float hn = (1.f - z) * hp[tz][jj] + z * hh;
                hp[tz][jj] = upd ? hn : hp[tz][jj];
            }
            uint2 q2;
            q2.x = cvt_pk_bf16(hp[tz][0], hp[tz][1]);
            q2.y = cvt_pk_bf16(hp[tz][2], hp[tz][3]);
            *WBA(tz) = q2;   // next step's B-frag source (in-order DS pipe)
            if (!AUG) *(uint2*)(horB + (size_t)t * 64 + 16 * tz + 4 * lg) = q2;
        }

        // ---- rotate prefetch ----
        if (GATHER) { ra0 = na0; ra1 = na1; rb0 = nb0; rb1 = nb1; idn = idn2; }
        else        { xc0 = nx0; xc1 = nx1; }
        if (AUG) sc = ns;
    }

    if (AUG) {
#pragma unroll
        for (int tz = 0; tz < 4; ++tz)
            *(f32x4*)(hfinal + (size_t)b * 64 + 16 * tz + 4 * lg) = hp[tz];
    } else {
        uint2 f0, f1, f2, f3;
        f0.x = cvt_pk_bf16(hp[0][0], hp[0][1]); f0.y = cvt_pk_bf16(hp[0][2], hp[0][3]);
        f1.x = cvt_pk_bf16(hp[1][0], hp[1][1]); f1.y = cvt_pk_bf16(hp[1][2], hp[1][3]);
        f2.x = cvt_pk_bf16(hp[2][0], hp[2][1]); f2.y = cvt_pk_bf16(hp[2][2], hp[2][3]);
        f3.x = cvt_pk_bf16(hp[3][0], hp[3][1]); f3.y = cvt_pk_bf16(hp[3][2], hp[3][3]);
        for (int t = tmax; t < TT; ++t) {
            *(uint2*)(horB + (size_t)t * 64 + 4 * lg) = f0;
            *(uint2*)(horB + (size_t)t * 64 + 16 + 4 * lg) = f1;
            *(uint2*)(horB + (size_t)t * 64 + 32 + 4 * lg) = f2;
            *(uint2*)(horB + (size_t)t * 64 + 48 + 4 * lg) = f3;
        }
    }
#undef WBA
#undef RBA
#undef RDS
}

// ---------------------------------------------------------------------------
// k_att: bf16 MFMA attention + fused softmax, len-clipped tiles (unchanged)
// ---------------------------------------------------------------------------
__global__ __launch_bounds__(256, 2) void k_att(
    const float* __restrict__ target, const unsigned short* __restrict__ seq_hb,
    const float* __restrict__ W1, const float* __restrict__ b1,
    const float* __restrict__ W2, const float* __restrict__ b2,
    const float* __restrict__ W3, const float* __restrict__ b3,
    const int* __restrict__ hist_len, float* __restrict__ scores)
{
    __shared__ unsigned short W1f[8 * 4 * 64 * 8];  // frag layout, 32 KB
    __shared__ float a1s[4][16][68];
    __shared__ float logit_lds[208];
    __shared__ float red[8];

    const int tid = threadIdx.x;
    const int wv = tid >> 6, l = tid & 63;
    const int lg = l >> 4, li = l & 15;
    const int b = blockIdx.x;
    const int len = hist_len[b];

    if (tid < 208) logit_lds[tid] = -1e9f;
    for (int i = tid; i < 8 * 4 * 64 * 8; i += 256) {
        int j = i & 7, ll = (i >> 3) & 63, nt = (i >> 9) & 3, c = i >> 11;
        int k = c * 32 + (ll >> 4) * 8 + j;
        int col = nt * 16 + (ll & 15);
        W1f[i] = f2bf(W1[k * 64 + col]);
    }
    __syncthreads();

    short8 w1r[8][4];
    const short8* wf = (const short8*)W1f;
#pragma unroll
    for (int c = 0; c < 8; ++c)
#pragma unroll
        for (int nt = 0; nt < 4; ++nt)
            w1r[c][nt] = wf[(c * 4 + nt) * 64 + l];

    short8 w2r[2];
#pragma unroll
    for (int c = 0; c < 2; ++c) {
        U8 t8;
#pragma unroll
        for (int m = 0; m < 4; ++m) {
            int k0 = c * 32 + lg * 8 + 2 * m;
            t8.u[m] = cvt_pk_bf16(W2[k0 * 16 + li], W2[(k0 + 1) * 16 + li]);
        }
        w2r[c] = t8.s8;
    }

    float b1v[4];
#pragma unroll
    for (int nt = 0; nt < 4; ++nt) b1v[nt] = b1[nt * 16 + li];
    const float b2v = b2[li];
    const float w3v = W3[li];
    const float b3r = b3[0];

    const float* qp = target + (size_t)b * 64;
    float qf_lo[8], qf_hi[8];
#pragma unroll
    for (int j = 0; j < 8; ++j) { qf_lo[j] = qp[lg * 8 + j]; qf_hi[j] = qp[32 + lg * 8 + j]; }
    U8 q8l, q8h;
#pragma unroll
    for (int m = 0; m < 4; ++m) {
        q8l.u[m] = cvt_pk_bf16(qf_lo[2 * m], qf_lo[2 * m + 1]);
        q8h.u[m] = cvt_pk_bf16(qf_hi[2 * m], qf_hi[2 * m + 1]);
    }

    for (int mt = wv; mt * 16 < len; mt += 4) {
        const int t = mt * 16 + li;
        const int tld = (t < TT) ? t : TT - 1;
        const unsigned short* hp = seq_hb + ((size_t)b * TT + tld) * 64 + lg * 8;
        short8 h8l = *(const short8*)hp;
        short8 h8h = *(const short8*)(hp + 32);

        U8 d8l, d8h, m8l, m8h;
#pragma unroll
        for (int m = 0; m < 4; ++m) {
            float h0, h1, d0, d1, p0, p1;
            h0 = bf2f((unsigned short)h8l[2 * m]); h1 = bf2f((unsigned short)h8l[2 * m + 1]);
            d0 = qf_lo[2 * m] - h0; d1 = qf_lo[2 * m + 1] - h1;
            p0 = qf_lo[2 * m] * h0; p1 = qf_lo[2 * m + 1] * h1;
            d8l.u[m] = cvt_pk_bf16(d0, d1);
            m8l.u[m] = cvt_pk_bf16(p0, p1);
            h0 = bf2f((unsigned short)h8h[2 * m]); h1 = bf2f((unsigned short)h8h[2 * m + 1]);
            d0 = qf_hi[2 * m] - h0; d1 = qf_hi[2 * m + 1] - h1;
            p0 = qf_hi[2 * m] * h0; p1 = qf_hi[2 * m + 1] * h1;
            d8h.u[m] = cvt_pk_bf16(d0, d1);
            m8h.u[m] = cvt_pk_bf16(p0, p1);
        }

        f32x4 acc[4];
#pragma unroll
        for (int nt = 0; nt < 4; ++nt) acc[nt] = (f32x4){0.f, 0.f, 0.f, 0.f};
#pragma unroll
        for (int nt = 0; nt < 4; ++nt) {
            acc[nt] = __builtin_amdgcn_mfma_f32_16x16x32_bf16(q8l.s8, w1r[0][nt], acc[nt], 0, 0, 0);
            acc[nt] = __builtin_amdgcn_mfma_f32_16x16x32_bf16(q8h.s8, w1r[1][nt], acc[nt], 0, 0, 0);
            acc[nt] = __builtin_amdgcn_mfma_f32_16x16x32_bf16(h8l,    w1r[2][nt], acc[nt], 0, 0, 0);
            acc[nt] = __builtin_amdgcn_mfma_f32_16x16x32_bf16(h8h,    w1r[3][nt], acc[nt], 0, 0, 0);
            acc[nt] = __builtin_amdgcn_mfma_f32_16x16x32_bf16(d8l.s8, w1r[4][nt], acc[nt], 0, 0, 0);
            acc[nt] = __builtin_amdgcn_mfma_f32_16x16x32_bf16(d8h.s8, w1r[5][nt], acc[nt], 0, 0, 0);
            acc[nt] = __builtin_amdgcn_mfma_f32_16x16x32_bf16(m8l.s8, w1r[6][nt], acc[nt], 0, 0, 0);
            acc[nt] = __builtin_amdgcn_mfma_f32_16x16x32_bf16(m8h.s8, w1r[7][nt], acc[nt], 0, 0, 0);
        }

#pragma unroll
        for (int nt = 0; nt < 4; ++nt)
#pragma unroll
            for (int jj = 0; jj < 4; ++jj) {
                float v = acc[nt][jj] + b1v[nt];
                a1s[wv][lg * 4 + jj][nt * 16 + li] = (v > 0.f) ? v : 0.25f * v;
            }

        const float* arow = &a1s[wv][li][0];
        f32x4 acc2 = (f32x4){0.f, 0.f, 0.f, 0.f};
#pragma unroll
        for (int c2 = 0; c2 < 2; ++c2) {
            f32x4 v0 = *(const f32x4*)(arow + c2 * 32 + lg * 8);
            f32x4 v1 = *(const f32x4*)(arow + c2 * 32 + lg * 8 + 4);
            U8 a2f;
            a2f.u[0] = cvt_pk_bf16(v0[0], v0[1]);
            a2f.u[1] = cvt_pk_bf16(v0[2], v0[3]);
            a2f.u[2] = cvt_pk_bf16(v1[0], v1[1]);
            a2f.u[3] = cvt_pk_bf16(v1[2], v1[3]);
            acc2 = __builtin_amdgcn_mfma_f32_16x16x32_bf16(a2f.s8, w2r[c2], acc2, 0, 0, 0);
        }

#pragma unroll
        for (int jj = 0; jj < 4; ++jj) {
            float a2 = acc2[jj] + b2v;
            a2 = (a2 > 0.f) ? a2 : 0.25f * a2;
            float part = a2 * w3v;
            part += __shfl_xor(part, 1);
            part += __shfl_xor(part, 2);
            part += __shfl_xor(part, 4);
            part += __shfl_xor(part, 8);
            int tt = mt * 16 + lg * 4 + jj;
            if (li == 0 && tt < TT)
                logit_lds[tt] = (tt < len) ? (part + b3r) : -1e9f;
        }
    }
    __syncthreads();

    float v = (tid < TT) ? logit_lds[tid] : -1e30f;
    float m = v;
#pragma unroll
    for (int s = 1; s < 64; s <<= 1) m = fmaxf(m, __shfl_xor(m, s));
    if (l == 0) red[wv] = m;
    __syncthreads();
    m = fmaxf(fmaxf(red[0], red[1]), fmaxf(red[2], red[3]));
    float e = (tid < TT) ? __expf(v - m) : 0.f;
    float sum = e;
#pragma unroll
    for (int s = 1; s < 64; s <<= 1) sum += __shfl_xor(sum, s);
    if (l == 0) red[4 + wv] = sum;
    __syncthreads();
    float inv = __fdividef(1.f, red[4] + red[5] + red[6] + red[7]);
    if (tid < TT) scores[(size_t)b * TT + tid] = e * inv;
}

// ---------------------------------------------------------------------------
// FFN chain (tiny, unchanged)
// ---------------------------------------------------------------------------
__global__ __launch_bounds__(256) void k_fc1(const float* __restrict__ fin,
                                             const float* __restrict__ tgt,
                                             const float* __restrict__ oth,
                                             const float* __restrict__ Wt,
                                             const float* __restrict__ bvec,
                                             float* __restrict__ fout) {
    __shared__ float z0[164];
    int b = blockIdx.x, tid = threadIdx.x;
    if (tid < 64) z0[tid] = fin[b * 64 + tid];
    else if (tid < 128) z0[tid] = tgt[b * 64 + tid - 64];
    else if (tid < 164) z0[tid] = oth[b * 36 + tid - 128];
    __syncthreads();
    float acc = bvec[tid];
#pragma unroll 4
    for (int k = 0; k < 164; ++k) acc += z0[k] * Wt[k * 256 + tid];
    fout[(size_t)b * 256 + tid] = acc;
}

template <int F>
__global__ __launch_bounds__(256) void k_stats(const float* __restrict__ x, float* __restrict__ stat) {
    int c = blockIdx.x, tid = threadIdx.x;
    float s = 0.f, sq = 0.f;
    for (int i = tid; i < BB; i += 256) {
        float v = x[(size_t)i * F + c];
        s += v; sq += v * v;
    }
#pragma unroll
    for (int m = 1; m < 64; m <<= 1) { s += __shfl_xor(s, m); sq += __shfl_xor(sq, m); }
    __shared__ float rs[4], rq[4];
    if ((tid & 63) == 0) { rs[tid >> 6] = s; rq[tid >> 6] = sq; }
    __syncthreads();
    if (tid == 0) {
        float S = rs[0] + rs[1] + rs[2] + rs[3];
        float Q = rq[0] + rq[1] + rq[2] + rq[3];
        float mean = S * (1.f / BB);
        float var = Q * (1.f / BB) - mean * mean;
        stat[c] = mean;
        stat[F + c] = var;
    }
}

__global__ __launch_bounds__(256) void k_fc2(const float* __restrict__ f1,
                                             const float* __restrict__ st1,
                                             const float* __restrict__ Wt,
                                             const float* __restrict__ bvec,
                                             float* __restrict__ f2) {
    __shared__ float z[256];
    int b = blockIdx.x, tid = threadIdx.x;
    float x = f1[(size_t)b * 256 + tid];
    z[tid] = dicef_(x, st1[tid], st1[256 + tid]);
    __syncthreads();
    if (tid < 128) {
        float acc = bvec[tid];
#pragma unroll 4
        for (int k = 0; k < 256; ++k) acc += z[k] * Wt[k * 128 + tid];
        f2[(size_t)b * 128 + tid] = acc;
    }
}

__global__ __launch_bounds__(128) void k_fc3(const float* __restrict__ f2,
                                             const float* __restrict__ st2,
                                             const float* __restrict__ Wt,
                                             const float* __restrict__ bvec,
                                             float* __restrict__ f3) {
    __shared__ float z[128];
    int b = blockIdx.x, tid = threadIdx.x;
    float x = f2[(size_t)b * 128 + tid];
    z[tid] = dicef_(x, st2[tid], st2[128 + tid]);
    __syncthreads();
    if (tid < 64) {
        float acc = bvec[tid];
#pragma unroll 4
        for (int k = 0; k < 128; ++k) acc += z[k] * Wt[k * 64 + tid];
        f3[(size_t)b * 64 + tid] = acc;
    }
}

__global__ void k_out(const float* __restrict__ f3, const float* __restrict__ st3,
                      const float* __restrict__ outW, const float* __restrict__ outb,
                      float* __restrict__ out) {
    int b = blockIdx.x, l = threadIdx.x;  // 64 threads
    float x = f3[(size_t)b * 64 + l];
    float z = dicef_(x, st3[l], st3[64 + l]);
    float p = z * outW[l];
#pragma unroll
    for (int m = 1; m < 64; m <<= 1) p += __shfl_xor(p, m);
    if (l == 0) out[b] = sigmoidf_(p + outb[0]);
}

// ---------------------------------------------------------------------------
extern "C" void kernel_launch(void* const* d_in, const int* in_sizes, int n_in,
                              void* d_out, int out_size, void* d_ws, size_t ws_size,
                              hipStream_t stream) {
    const float* dense      = (const float*)d_in[0];
    const int*   sparse     = (const int*)d_in[1];
    const int*   seq_idx    = (const int*)d_in[2];
    const int*   item_idx   = (const int*)d_in[3];
    const int*   hist_len   = (const int*)d_in[4];
    const float* item_table = (const float*)d_in[5];
    const float* other_tab  = (const float*)d_in[6];
    const float* gru_W = (const float*)d_in[7];
    const float* gru_U = (const float*)d_in[8];
    const float* gru_b = (const float*)d_in[9];
    const float* aug_W = (const float*)d_in[10];
    const float* aug_U = (const float*)d_in[11];
    const float* aug_b = (const float*)d_in[12];
    const float* att_W1 = (const float*)d_in[13];
    const float* att_b1 = (const float*)d_in[14];
    const float* att_W2 = (const float*)d_in[15];
    const float* att_b2 = (const float*)d_in[16];
    const float* att_W3 = (const float*)d_in[17];
    const float* att_b3 = (const float*)d_in[18];
    const float* ffn_W1 = (const float*)d_in[19];
    const float* ffn_b1 = (const float*)d_in[20];
    const float* ffn_W2 = (const float*)d_in[21];
    const float* ffn_b2 = (const float*)d_in[22];
    const float* ffn_W3 = (const float*)d_in[23];
    const float* ffn_b3 = (const float*)d_in[24];
    const float* out_W  = (const float*)d_in[25];
    const float* out_b  = (const float*)d_in[26];

    float* wsf = (float*)d_ws;
    unsigned short* seqhb = (unsigned short*)(wsf + 19660800);   // (B,T,64) bf16
    float* scores = wsf + 26214400;            // B*T
    float* target = wsf + 26419200;            // B*64
    float* other  = wsf + 26484736;            // B*36
    float* finals = wsf + 26521600;            // B*64
    float* f1     = wsf + 26587136;            // B*256
    float* f2     = wsf + 26849280;            // B*128
    float* f3     = wsf + 26980352;            // B*64
    float* st1    = wsf + 27045888;            // 512
    float* st2    = wsf + 27046400;            // 256
    float* st3    = wsf + 27046656;            // 128

    float* dout = (float*)d_out;

    k_prep<<<BB, 64, 0, stream>>>(dense, sparse, item_idx, item_table, other_tab, target, other);

    // GRU1: fused gather + xW + recurrence -> seq_h bf16 (B,T,64)
    k_scanM<1, 0><<<BB / 16, 64, 0, stream>>>(seq_idx, item_table, nullptr,
                                              gru_U, gru_W, gru_b, hist_len,
                                              nullptr, seqhb, nullptr);

    // attention MLP (MFMA) + fused softmax -> scores
    k_att<<<BB, 256, 0, stream>>>(target, seqhb, att_W1, att_b1, att_W2, att_b2,
                                  att_W3, att_b3, hist_len, scores);

    // AUGRU: fused xW + recurrence -> finals f32 (B,64)
    k_scanM<0, 1><<<BB / 16, 64, 0, stream>>>(nullptr, nullptr, seqhb,
                                              aug_U, aug_W, aug_b, hist_len,
                                              scores, nullptr, finals);

    k_fc1<<<BB, 256, 0, stream>>>(finals, target, other, ffn_W1, ffn_b1, f1);
    k_stats<256><<<256, 256, 0, stream>>>(f1, st1);
    k_fc2<<<BB, 256, 0, stream>>>(f1, st1, ffn_W2, ffn_b2, f2);
    k_stats<128><<<128, 256, 0, stream>>>(f2, st2);
    k_fc3<<<BB, 128, 0, stream>>>(f2, st2, ffn_W3, ffn_b3, f3);
    k_stats<64><<<64, 256, 0, stream>>>(f3, st3);
    k_out<<<BB, 64, 0, stream>>>(f3, st3, out_W, out_b, dout);
}

// Round 18
// 1013.689 us; speedup vs baseline: 1.0030x; 1.0030x over previous
//
#include <hip/hip_runtime.h>

#define BB 1024
#define TT 200

typedef __attribute__((ext_vector_type(8))) short short8;
typedef __attribute__((ext_vector_type(2))) short short2v;
typedef __attribute__((ext_vector_type(4))) float f32x4;
typedef __attribute__((ext_vector_type(4))) unsigned uint4v;

__device__ __forceinline__ float sigmoidf_(float x) { return __fdividef(1.0f, 1.0f + __expf(-x)); }
__device__ __forceinline__ float tanh_fast(float x) {
    x = fminf(15.f, fmaxf(-15.f, x));
    float e = __expf(-2.f * x);
    return __fdividef(1.f - e, 1.f + e);
}
__device__ __forceinline__ float dicef_(float x, float m, float v) {
    return x * sigmoidf_((x - m) * rsqrtf(v + 1e-9f));
}
__device__ __forceinline__ unsigned short f2bf(float f) {
    unsigned u = __float_as_uint(f);
    unsigned r = u + 0x7fffu + ((u >> 16) & 1u);
    return (unsigned short)(r >> 16);
}
__device__ __forceinline__ float bf2f(unsigned short h) {
    return __uint_as_float(((unsigned)h) << 16);
}
__device__ __forceinline__ unsigned cvt_pk_bf16(float lo, float hi) {
    unsigned r;
    asm("v_cvt_pk_bf16_f32 %0, %1, %2" : "=v"(r) : "v"(lo), "v"(hi));
    return r;
}
union U8 { short8 s8; unsigned u[4]; };
union UU { short8 s8v; uint4v u4; uint2 u2[2]; };

// ---------------------------------------------------------------------------
// k_prep
// ---------------------------------------------------------------------------
__global__ void k_prep(const float* __restrict__ dense, const int* __restrict__ sparse,
                       const int* __restrict__ item_idx, const float* __restrict__ table,
                       const float* __restrict__ other_tables,
                       float* __restrict__ target, float* __restrict__ other) {
    int b = blockIdx.x, l = threadIdx.x;  // 64 threads
    target[b * 64 + l] = table[(size_t)item_idx[b] * 64 + l];
    if (l < 4) other[b * 36 + l] = dense[b * 4 + l];
    else if (l < 20) other[b * 36 + l] = other_tables[(size_t)sparse[b * 2 + 0] * 16 + (l - 4)];
    else if (l < 36) other[b * 36 + l] = other_tables[1000 * 16 + (size_t)sparse[b * 2 + 1] * 16 + (l - 20)];
}

// ---------------------------------------------------------------------------
// k_xw: XW = X @ W + bias, bf16 MFMA, masked-tile skip (r12 version)
// ---------------------------------------------------------------------------
template <int GATHER>
__global__ __launch_bounds__(256, 1) void k_xw(
    const int* __restrict__ idx, const float* __restrict__ tablef,
    const unsigned short* __restrict__ Abf,
    const float* __restrict__ W, const float* __restrict__ bias,
    const int* __restrict__ hist_len,
    unsigned short* __restrict__ out, int Mtiles, int tilestride)
{
    const int l = threadIdx.x & 63;
    const int wv = threadIdx.x >> 6;
    const int lg = l >> 4;
    const int li = l & 15;

    short8 bfr[12][2];
    float bn[12];
#pragma unroll
    for (int nt = 0; nt < 12; ++nt) {
        bn[nt] = bias[nt * 16 + li];
#pragma unroll
        for (int c = 0; c < 2; ++c) {
#pragma unroll
            for (int j = 0; j < 8; ++j) {
                int k = c * 32 + lg * 8 + j;
                bfr[nt][c][j] = (short)f2bf(W[k * 192 + nt * 16 + li]);
            }
        }
    }

    for (int tile = blockIdx.x * 4 + wv; tile < Mtiles; tile += tilestride) {
        long row = (long)tile * 16 + li;
        {
            int bb = (int)(row / TT);
            int tt = (int)(row - (long)bb * TT);
            int vld = (tt < hist_len[bb]) ? 1 : 0;
            if (__ballot(vld) == 0ull) continue;
        }

        short8 a[2];
        if (GATHER) {
            long id = idx[row];
            const float* tp = tablef + id * 64 + lg * 8;
#pragma unroll
            for (int c = 0; c < 2; ++c) {
                f32x4 v0 = *(const f32x4*)(tp + c * 32);
                f32x4 v1 = *(const f32x4*)(tp + c * 32 + 4);
#pragma unroll
                for (int j = 0; j < 4; ++j) {
                    a[c][j] = (short)f2bf(v0[j]);
                    a[c][4 + j] = (short)f2bf(v1[j]);
                }
            }
        } else {
#pragma unroll
            for (int c = 0; c < 2; ++c)
                a[c] = *(const short8*)(Abf + row * 64 + c * 32 + lg * 8);
        }

        f32x4 acc[12];
#pragma unroll
        for (int nt = 0; nt < 12; ++nt) acc[nt] = (f32x4){0.f, 0.f, 0.f, 0.f};
#pragma unroll
        for (int c = 0; c < 2; ++c)
#pragma unroll
            for (int nt = 0; nt < 12; ++nt)
                acc[nt] = __builtin_amdgcn_mfma_f32_16x16x32_bf16(a[c], bfr[nt][c], acc[nt], 0, 0, 0);

#pragma unroll
        for (int nt = 0; nt < 12; ++nt)
#pragma unroll
            for (int j = 0; j < 4; ++j) {
                long orow = (long)tile * 16 + lg * 4 + j;
                out[orow * 192 + nt * 16 + li] = f2bf(acc[nt][j] + bn[nt]);
            }
    }
}

// ---------------------------------------------------------------------------
// k_scanU: MFMA recurrence, ONE WAVE per 16 batch rows, zero barriers.
// r17's HW-verified layouts (A/B/C frags, swizzled hbuf exchange, U image)
// + r16's asm batching: ONE asm block per step issues 2 h-frag + 24 U-frag
// ds_read_b128 (8 swizzled addr regs x offsets 0/128/256) + single
// lgkmcnt(0). MFMAs consume asm OUTPUTS (register dep -> cannot hoist).
// This removes r17's killer: 24 dependent RDS->MFMA latency exposures
// (~6000cy/step) collapse to one (~650cy/step for 16 rows).
// xw (=x@W+bias, from k_xw) is added at gate time via 12 prefetched b64
// global loads (1-step-ahead, hidden under the step).
// AUG=1: z *= scores[row][t], writes hfinal. Else writes hout + tail fill.
// ---------------------------------------------------------------------------
template <int AUG>
__global__ __launch_bounds__(64, 1) void k_scanU(
    const unsigned short* __restrict__ xw,   // (B*T,192) bf16 (bias included)
    const float* __restrict__ U,             // (64,192)
    const int* __restrict__ hist_len,
    const float* __restrict__ scores,        // (B,T) when AUG
    unsigned short* __restrict__ hout,       // (B,T,64) bf16 (!AUG)
    float* __restrict__ hfinal)              // (B,64) f32 (AUG)
{
    __shared__ unsigned Ul[64 * 96];             // 24 KB U A-frag image
    __shared__ unsigned short hbuf[16 * 64];     // 2 KB h exchange (swizzled)

    const int l = threadIdx.x, lg = l >> 4, li = l & 15;
    const unsigned s8 = (unsigned)l & 7u;
    const int b = blockIdx.x * 16 + li;
    const int len = hist_len[b];
    int tmax = len;
#pragma unroll
    for (int m = 1; m < 64; m <<= 1) { int o = __shfl_xor(tmax, m); tmax = (o > tmax) ? o : tmax; }

    unsigned* lb = Ul + l * 96;
    // stage U^T A-frags: slot s=mt*2+c at position (s&~7)|((s&7)^s8)  (r17)
    for (int mt = 0; mt < 12; ++mt) {
        const int col = mt * 16 + li;
        for (int c = 0; c < 2; ++c) {
            UU fu;
#pragma unroll
            for (int j = 0; j < 8; ++j) {
                int k = c * 32 + lg * 8 + j;
                fu.s8v[j] = (short)f2bf(U[k * 192 + col]);
            }
            const int s = mt * 2 + c;
            ((uint4v*)lb)[(unsigned)(s & ~7) | (((unsigned)s & 7u) ^ s8)] = fu.u4;
        }
    }

    // h exchange addresses (r17 pattern, verified)
    char* hbB = (char*)hbuf + li * 128;
#define WBA(tz) ((uint2*)(hbB + ((((tz) * 32 + lg * 8)) ^ (s8 << 4))))
    const unsigned h0a = (unsigned)(unsigned long long)(void*)(hbB + ((0 * 64 + lg * 16) ^ (s8 << 4)));
    const unsigned h1a = (unsigned)(unsigned long long)(void*)(hbB + ((1 * 64 + lg * 16) ^ (s8 << 4)));
    // U asm addresses: slot s=8g+q at lb + (q^s8)*16 + g*128
    const unsigned ubase = (unsigned)(unsigned long long)(void*)lb;
    const unsigned ua0 = ubase + ((0u ^ s8) << 4);
    const unsigned ua1 = ubase + ((1u ^ s8) << 4);
    const unsigned ua2 = ubase + ((2u ^ s8) << 4);
    const unsigned ua3 = ubase + ((3u ^ s8) << 4);
    const unsigned ua4 = ubase + ((4u ^ s8) << 4);
    const unsigned ua5 = ubase + ((5u ^ s8) << 4);
    const unsigned ua6 = ubase + ((6u ^ s8) << 4);
    const unsigned ua7 = ubase + ((7u ^ s8) << 4);

    {
        uint2 z2; z2.x = 0u; z2.y = 0u;
#pragma unroll
        for (int tz = 0; tz < 4; ++tz) *WBA(tz) = z2;
    }

    f32x4 hp[4];
#pragma unroll
    for (int tz = 0; tz < 4; ++tz) hp[tz] = (f32x4){0.f, 0.f, 0.f, 0.f};

    // xw prefetch: lane (lg,li) needs dims sect*64 + 16tz + 4lg (4 ushorts = b64)
    const unsigned short* xwr = xw + (size_t)b * TT * 192;
    const float* scr = AUG ? (scores + (size_t)b * TT) : nullptr;
    uint2 cxw[12], nxw[12];
    float cs = 0.f, ns = 0.f;
#pragma unroll
    for (int g = 0; g < 3; ++g)
#pragma unroll
        for (int tz = 0; tz < 4; ++tz)
            cxw[g * 4 + tz] = *(const uint2*)(xwr + g * 64 + 16 * tz + 4 * lg);
    if (AUG) cs = scr[0];

    unsigned short* horB = hout + (size_t)b * TT * 64;

    for (int t = 0; t < tmax; ++t) {
        // ---- batched LDS reads: 2 h-frags + 24 U-frags, ONE drain ----
        uint4v hbr0, hbr1;
        UU uf[24];
        asm volatile(
            "ds_read_b128 %0, %26\n\t"
            "ds_read_b128 %1, %27\n\t"
            "ds_read_b128 %2, %28\n\t"
            "ds_read_b128 %3, %29\n\t"
            "ds_read_b128 %4, %30\n\t"
            "ds_read_b128 %5, %31\n\t"
            "ds_read_b128 %6, %32\n\t"
            "ds_read_b128 %7, %33\n\t"
            "ds_read_b128 %8, %34\n\t"
            "ds_read_b128 %9, %35\n\t"
            "ds_read_b128 %10, %28 offset:128\n\t"
            "ds_read_b128 %11, %29 offset:128\n\t"
            "ds_read_b128 %12, %30 offset:128\n\t"
            "ds_read_b128 %13, %31 offset:128\n\t"
            "ds_read_b128 %14, %32 offset:128\n\t"
            "ds_read_b128 %15, %33 offset:128\n\t"
            "ds_read_b128 %16, %34 offset:128\n\t"
            "ds_read_b128 %17, %35 offset:128\n\t"
            "ds_read_b128 %18, %28 offset:256\n\t"
            "ds_read_b128 %19, %29 offset:256\n\t"
            "ds_read_b128 %20, %30 offset:256\n\t"
            "ds_read_b128 %21, %31 offset:256\n\t"
            "ds_read_b128 %22, %32 offset:256\n\t"
            "ds_read_b128 %23, %33 offset:256\n\t"
            "ds_read_b128 %24, %34 offset:256\n\t"
            "ds_read_b128 %25, %35 offset:256\n\t"
            "s_waitcnt lgkmcnt(0)"
            : "=&v"(hbr0), "=&v"(hbr1),
              "=&v"(uf[0].u4), "=&v"(uf[1].u4), "=&v"(uf[2].u4), "=&v"(uf[3].u4),
              "=&v"(uf[4].u4), "=&v"(uf[5].u4), "=&v"(uf[6].u4), "=&v"(uf[7].u4),
              "=&v"(uf[8].u4), "=&v"(uf[9].u4), "=&v"(uf[10].u4), "=&v"(uf[11].u4),
              "=&v"(uf[12].u4), "=&v"(uf[13].u4), "=&v"(uf[14].u4), "=&v"(uf[15].u4),
              "=&v"(uf[16].u4), "=&v"(uf[17].u4), "=&v"(uf[18].u4), "=&v"(uf[19].u4),
              "=&v"(uf[20].u4), "=&v"(uf[21].u4), "=&v"(uf[22].u4), "=&v"(uf[23].u4)
            : "v"(h0a), "v"(h1a),
              "v"(ua0), "v"(ua1), "v"(ua2), "v"(ua3),
              "v"(ua4), "v"(ua5), "v"(ua6), "v"(ua7)
            : "memory");
        UU hb0, hb1;
        hb0.u4 = hbr0;
        hb1.u4 = hbr1;

        // ---- issue next-step xw loads (hidden under MFMAs/gates) ----
        {
            const int tn = (t + 1 < TT) ? (t + 1) : (TT - 1);
            const unsigned short* xp = xwr + (size_t)tn * 192;
#pragma unroll
            for (int g = 0; g < 3; ++g)
#pragma unroll
                for (int tz = 0; tz < 4; ++tz)
                    nxw[g * 4 + tz] = *(const uint2*)(xp + g * 64 + 16 * tz + 4 * lg);
            if (AUG) ns = scr[tn];
        }

        // ---- 24 MFMAs (12 tiles x 2 K-chunks); slot s = mt*2+c -> uf[s] ----
        f32x4 am[12];
#pragma unroll
        for (int mt = 0; mt < 12; ++mt) {
            f32x4 acc = (f32x4){0.f, 0.f, 0.f, 0.f};
            acc = __builtin_amdgcn_mfma_f32_16x16x32_bf16(uf[mt * 2].s8v,     hb0.s8v, acc, 0, 0, 0);
            acc = __builtin_amdgcn_mfma_f32_16x16x32_bf16(uf[mt * 2 + 1].s8v, hb1.s8v, acc, 0, 0, 0);
            am[mt] = acc;
        }

        // ---- gates (lane-local; xw already includes bias) ----
        const bool upd = (t < len);
#pragma unroll
        for (int tz = 0; tz < 4; ++tz) {
#pragma unroll
            for (int jj = 0; jj < 4; ++jj) {
                const unsigned xzw = (jj < 2) ? cxw[tz].x : cxw[tz].y;
                const unsigned xrw = (jj < 2) ? cxw[4 + tz].x : cxw[4 + tz].y;
                const unsigned xhw = (jj < 2) ? cxw[8 + tz].x : cxw[8 + tz].y;
                const int sh = (jj & 1) * 16;
                float xz = bf2f((unsigned short)(xzw >> sh));
                float xr = bf2f((unsigned short)(xrw >> sh));
                float xh = bf2f((unsigned short)(xhw >> sh));
                float z = sigmoidf_(xz + am[tz][jj]);
                if (AUG) z *= cs;
                float r = sigmoidf_(xr + am[4 + tz][jj]);
                float hh = tanh_fast(xh + r * am[8 + tz][jj]);
                float hn = (1.f - z) * hp[tz][jj] + z * hh;
                hp[tz][jj] = upd ? hn : hp[tz][jj];
            }
            uint2 q2;
            q2.x = cvt_pk_bf16(hp[tz][0], hp[tz][1]);
            q2.y = cvt_pk_bf16(hp[tz][2], hp[tz][3]);
            *WBA(tz) = q2;   // next step's B-frag source (in-order DS pipe)
            if (!AUG) *(uint2*)(horB + (size_t)t * 64 + 16 * tz + 4 * lg) = q2;
        }

        // rotate xw prefetch
#pragma unroll
        for (int i = 0; i < 12; ++i) cxw[i] = nxw[i];
        if (AUG) cs = ns;
    }

    if (AUG) {
#pragma unroll
        for (int tz = 0; tz < 4; ++tz)
            *(f32x4*)(hfinal + (size_t)b * 64 + 16 * tz + 4 * lg) = hp[tz];
    } else {
        uint2 f0, f1, f2, f3;
        f0.x = cvt_pk_bf16(hp[0][0], hp[0][1]); f0.y = cvt_pk_bf16(hp[0][2], hp[0][3]);
        f1.x = cvt_pk_bf16(hp[1][0], hp[1][1]); f1.y = cvt_pk_bf16(hp[1][2], hp[1][3]);
        f2.x = cvt_pk_bf16(hp[2][0], hp[2][1]); f2.y = cvt_pk_bf16(hp[2][2], hp[2][3]);
        f3.x = cvt_pk_bf16(hp[3][0], hp[3][1]); f3.y = cvt_pk_bf16(hp[3][2], hp[3][3]);
        for (int t = tmax; t < TT; ++t) {
            *(uint2*)(horB + (size_t)t * 64 + 4 * lg) = f0;
            *(uint2*)(horB + (size_t)t * 64 + 16 + 4 * lg) = f1;
            *(uint2*)(horB + (size_t)t * 64 + 32 + 4 * lg) = f2;
            *(uint2*)(horB + (size_t)t * 64 + 48 + 4 * lg) = f3;
        }
    }
#undef WBA
}

// ---------------------------------------------------------------------------
// k_att: bf16 MFMA attention + fused softmax, len-clipped tiles (unchanged)
// ---------------------------------------------------------------------------
__global__ __launch_bounds__(256, 2) void k_att(
    const float* __restrict__ target, const unsigned short* __restrict__ seq_hb,
    const float* __restrict__ W1, const float* __restrict__ b1,
    const float* __restrict__ W2, const float* __restrict__ b2,
    const float* __restrict__ W3, const float* __restrict__ b3,
    const int* __restrict__ hist_len, float* __restrict__ scores)
{
    __shared__ unsigned short W1f[8 * 4 * 64 * 8];  // frag layout, 32 KB
    __shared__ float a1s[4][16][68];
    __shared__ float logit_lds[208];
    __shared__ float red[8];

    const int tid = threadIdx.x;
    const int wv = tid >> 6, l = tid & 63;
    const int lg = l >> 4, li = l & 15;
    const int b = blockIdx.x;
    const int len = hist_len[b];

    if (tid < 208) logit_lds[tid] = -1e9f;
    for (int i = tid; i < 8 * 4 * 64 * 8; i += 256) {
        int j = i & 7, ll = (i >> 3) & 63, nt = (i >> 9) & 3, c = i >> 11;
        int k = c * 32 + (ll >> 4) * 8 + j;
        int col = nt * 16 + (ll & 15);
        W1f[i] = f2bf(W1[k * 64 + col]);
    }
    __syncthreads();

    short8 w1r[8][4];
    const short8* wf = (const short8*)W1f;
#pragma unroll
    for (int c = 0; c < 8; ++c)
#pragma unroll
        for (int nt = 0; nt < 4; ++nt)
            w1r[c][nt] = wf[(c * 4 + nt) * 64 + l];

    short8 w2r[2];
#pragma unroll
    for (int c = 0; c < 2; ++c) {
        U8 t8;
#pragma unroll
        for (int m = 0; m < 4; ++m) {
            int k0 = c * 32 + lg * 8 + 2 * m;
            t8.u[m] = cvt_pk_bf16(W2[k0 * 16 + li], W2[(k0 + 1) * 16 + li]);
        }
        w2r[c] = t8.s8;
    }

    float b1v[4];
#pragma unroll
    for (int nt = 0; nt < 4; ++nt) b1v[nt] = b1[nt * 16 + li];
    const float b2v = b2[li];
    const float w3v = W3[li];
    const float b3r = b3[0];

    const float* qp = target + (size_t)b * 64;
    float qf_lo[8], qf_hi[8];
#pragma unroll
    for (int j = 0; j < 8; ++j) { qf_lo[j] = qp[lg * 8 + j]; qf_hi[j] = qp[32 + lg * 8 + j]; }
    U8 q8l, q8h;
#pragma unroll
    for (int m = 0; m < 4; ++m) {
        q8l.u[m] = cvt_pk_bf16(qf_lo[2 * m], qf_lo[2 * m + 1]);
        q8h.u[m] = cvt_pk_bf16(qf_hi[2 * m], qf_hi[2 * m + 1]);
    }

    for (int mt = wv; mt * 16 < len; mt += 4) {
        const int t = mt * 16 + li;
        const int tld = (t < TT) ? t : TT - 1;
        const unsigned short* hp = seq_hb + ((size_t)b * TT + tld) * 64 + lg * 8;
        short8 h8l = *(const short8*)hp;
        short8 h8h = *(const short8*)(hp + 32);

        U8 d8l, d8h, m8l, m8h;
#pragma unroll
        for (int m = 0; m < 4; ++m) {
            float h0, h1, d0, d1, p0, p1;
            h0 = bf2f((unsigned short)h8l[2 * m]); h1 = bf2f((unsigned short)h8l[2 * m + 1]);
            d0 = qf_lo[2 * m] - h0; d1 = qf_lo[2 * m + 1] - h1;
            p0 = qf_lo[2 * m] * h0; p1 = qf_lo[2 * m + 1] * h1;
            d8l.u[m] = cvt_pk_bf16(d0, d1);
            m8l.u[m] = cvt_pk_bf16(p0, p1);
            h0 = bf2f((unsigned short)h8h[2 * m]); h1 = bf2f((unsigned short)h8h[2 * m + 1]);
            d0 = qf_hi[2 * m] - h0; d1 = qf_hi[2 * m + 1] - h1;
            p0 = qf_hi[2 * m] * h0; p1 = qf_hi[2 * m + 1] * h1;
            d8h.u[m] = cvt_pk_bf16(d0, d1);
            m8h.u[m] = cvt_pk_bf16(p0, p1);
        }

        f32x4 acc[4];
#pragma unroll
        for (int nt = 0; nt < 4; ++nt) acc[nt] = (f32x4){0.f, 0.f, 0.f, 0.f};
#pragma unroll
        for (int nt = 0; nt < 4; ++nt) {
            acc[nt] = __builtin_amdgcn_mfma_f32_16x16x32_bf16(q8l.s8, w1r[0][nt], acc[nt], 0, 0, 0);
            acc[nt] = __builtin_amdgcn_mfma_f32_16x16x32_bf16(q8h.s8, w1r[1][nt], acc[nt], 0, 0, 0);
            acc[nt] = __builtin_amdgcn_mfma_f32_16x16x32_bf16(h8l,    w1r[2][nt], acc[nt], 0, 0, 0);
            acc[nt] = __builtin_amdgcn_mfma_f32_16x16x32_bf16(h8h,    w1r[3][nt], acc[nt], 0, 0, 0);
            acc[nt] = __builtin_amdgcn_mfma_f32_16x16x32_bf16(d8l.s8, w1r[4][nt], acc[nt], 0, 0, 0);
            acc[nt] = __builtin_amdgcn_mfma_f32_16x16x32_bf16(d8h.s8, w1r[5][nt], acc[nt], 0, 0, 0);
            acc[nt] = __builtin_amdgcn_mfma_f32_16x16x32_bf16(m8l.s8, w1r[6][nt], acc[nt], 0, 0, 0);
            acc[nt] = __builtin_amdgcn_mfma_f32_16x16x32_bf16(m8h.s8, w1r[7][nt], acc[nt], 0, 0, 0);
        }

#pragma unroll
        for (int nt = 0; nt < 4; ++nt)
#pragma unroll
            for (int jj = 0; jj < 4; ++jj) {
                float v = acc[nt][jj] + b1v[nt];
                a1s[wv][lg * 4 + jj][nt * 16 + li] = (v > 0.f) ? v : 0.25f * v;
            }

        const float* arow = &a1s[wv][li][0];
        f32x4 acc2 = (f32x4){0.f, 0.f, 0.f, 0.f};
#pragma unroll
        for (int c2 = 0; c2 < 2; ++c2) {
            f32x4 v0 = *(const f32x4*)(arow + c2 * 32 + lg * 8);
            f32x4 v1 = *(const f32x4*)(arow + c2 * 32 + lg * 8 + 4);
            U8 a2f;
            a2f.u[0] = cvt_pk_bf16(v0[0], v0[1]);
            a2f.u[1] = cvt_pk_bf16(v0[2], v0[3]);
            a2f.u[2] = cvt_pk_bf16(v1[0], v1[1]);
            a2f.u[3] = cvt_pk_bf16(v1[2], v1[3]);
            acc2 = __builtin_amdgcn_mfma_f32_16x16x32_bf16(a2f.s8, w2r[c2], acc2, 0, 0, 0);
        }

#pragma unroll
        for (int jj = 0; jj < 4; ++jj) {
            float a2 = acc2[jj] + b2v;
            a2 = (a2 > 0.f) ? a2 : 0.25f * a2;
            float part = a2 * w3v;
            part += __shfl_xor(part, 1);
            part += __shfl_xor(part, 2);
            part += __shfl_xor(part, 4);
            part += __shfl_xor(part, 8);
            int tt = mt * 16 + lg * 4 + jj;
            if (li == 0 && tt < TT)
                logit_lds[tt] = (tt < len) ? (part + b3r) : -1e9f;
        }
    }
    __syncthreads();

    float v = (tid < TT) ? logit_lds[tid] : -1e30f;
    float m = v;
#pragma unroll
    for (int s = 1; s < 64; s <<= 1) m = fmaxf(m, __shfl_xor(m, s));
    if (l == 0) red[wv] = m;
    __syncthreads();
    m = fmaxf(fmaxf(red[0], red[1]), fmaxf(red[2], red[3]));
    float e = (tid < TT) ? __expf(v - m) : 0.f;
    float sum = e;
#pragma unroll
    for (int s = 1; s < 64; s <<= 1) sum += __shfl_xor(sum, s);
    if (l == 0) red[4 + wv] = sum;
    __syncthreads();
    float inv = __fdividef(1.f, red[4] + red[5] + red[6] + red[7]);
    if (tid < TT) scores[(size_t)b * TT + tid] = e * inv;
}

// ---------------------------------------------------------------------------
// FFN chain (tiny, unchanged)
// ---------------------------------------------------------------------------
__global__ __launch_bounds__(256) void k_fc1(const float* __restrict__ fin,
                                             const float* __restrict__ tgt,
                                             const float* __restrict__ oth,
                                             const float* __restrict__ Wt,
                                             const float* __restrict__ bvec,
                                             float* __restrict__ fout) {
    __shared__ float z0[164];
    int b = blockIdx.x, tid = threadIdx.x;
    if (tid < 64) z0[tid] = fin[b * 64 + tid];
    else if (tid < 128) z0[tid] = tgt[b * 64 + tid - 64];
    else if (tid < 164) z0[tid] = oth[b * 36 + tid - 128];
    __syncthreads();
    float acc = bvec[tid];
#pragma unroll 4
    for (int k = 0; k < 164; ++k) acc += z0[k] * Wt[k * 256 + tid];
    fout[(size_t)b * 256 + tid] = acc;
}

template <int F>
__global__ __launch_bounds__(256) void k_stats(const float* __restrict__ x, float* __restrict__ stat) {
    int c = blockIdx.x, tid = threadIdx.x;
    float s = 0.f, sq = 0.f;
    for (int i = tid; i < BB; i += 256) {
        float v = x[(size_t)i * F + c];
        s += v; sq += v * v;
    }
#pragma unroll
    for (int m = 1; m < 64; m <<= 1) { s += __shfl_xor(s, m); sq += __shfl_xor(sq, m); }
    __shared__ float rs[4], rq[4];
    if ((tid & 63) == 0) { rs[tid >> 6] = s; rq[tid >> 6] = sq; }
    __syncthreads();
    if (tid == 0) {
        float S = rs[0] + rs[1] + rs[2] + rs[3];
        float Q = rq[0] + rq[1] + rq[2] + rq[3];
        float mean = S * (1.f / BB);
        float var = Q * (1.f / BB) - mean * mean;
        stat[c] = mean;
        stat[F + c] = var;
    }
}

__global__ __launch_bounds__(256) void k_fc2(const float* __restrict__ f1,
                                             const float* __restrict__ st1,
                                             const float* __restrict__ Wt,
                                             const float* __restrict__ bvec,
                                             float* __restrict__ f2) {
    __shared__ float z[256];
    int b = blockIdx.x, tid = threadIdx.x;
    float x = f1[(size_t)b * 256 + tid];
    z[tid] = dicef_(x, st1[tid], st1[256 + tid]);
    __syncthreads();
    if (tid < 128) {
        float acc = bvec[tid];
#pragma unroll 4
        for (int k = 0; k < 256; ++k) acc += z[k] * Wt[k * 128 + tid];
        f2[(size_t)b * 128 + tid] = acc;
    }
}

__global__ __launch_bounds__(128) void k_fc3(const float* __restrict__ f2,
                                             const float* __restrict__ st2,
                                             const float* __restrict__ Wt,
                                             const float* __restrict__ bvec,
                                             float* __restrict__ f3) {
    __shared__ float z[128];
    int b = blockIdx.x, tid = threadIdx.x;
    float x = f2[(size_t)b * 128 + tid];
    z[tid] = dicef_(x, st2[tid], st2[128 + tid]);
    __syncthreads();
    if (tid < 64) {
        float acc = bvec[tid];
#pragma unroll 4
        for (int k = 0; k < 128; ++k) acc += z[k] * Wt[k * 64 + tid];
        f3[(size_t)b * 64 + tid] = acc;
    }
}

__global__ void k_out(const float* __restrict__ f3, const float* __restrict__ st3,
                      const float* __restrict__ outW, const float* __restrict__ outb,
                      float* __restrict__ out) {
    int b = blockIdx.x, l = threadIdx.x;  // 64 threads
    float x = f3[(size_t)b * 64 + l];
    float z = dicef_(x, st3[l], st3[64 + l]);
    float p = z * outW[l];
#pragma unroll
    for (int m = 1; m < 64; m <<= 1) p += __shfl_xor(p, m);
    if (l == 0) out[b] = sigmoidf_(p + outb[0]);
}

// ---------------------------------------------------------------------------
extern "C" void kernel_launch(void* const* d_in, const int* in_sizes, int n_in,
                              void* d_out, int out_size, void* d_ws, size_t ws_size,
                              hipStream_t stream) {
    const float* dense      = (const float*)d_in[0];
    const int*   sparse     = (const int*)d_in[1];
    const int*   seq_idx    = (const int*)d_in[2];
    const int*   item_idx   = (const int*)d_in[3];
    const int*   hist_len   = (const int*)d_in[4];
    const float* item_table = (const float*)d_in[5];
    const float* other_tab  = (const float*)d_in[6];
    const float* gru_W = (const float*)d_in[7];
    const float* gru_U = (const float*)d_in[8];
    const float* gru_b = (const float*)d_in[9];
    const float* aug_W = (const float*)d_in[10];
    const float* aug_U = (const float*)d_in[11];
    const float* aug_b = (const float*)d_in[12];
    const float* att_W1 = (const float*)d_in[13];
    const float* att_b1 = (const float*)d_in[14];
    const float* att_W2 = (const float*)d_in[15];
    const float* att_b2 = (const float*)d_in[16];
    const float* att_W3 = (const float*)d_in[17];
    const float* att_b3 = (const float*)d_in[18];
    const float* ffn_W1 = (const float*)d_in[19];
    const float* ffn_b1 = (const float*)d_in[20];
    const float* ffn_W2 = (const float*)d_in[21];
    const float* ffn_b2 = (const float*)d_in[22];
    const float* ffn_W3 = (const float*)d_in[23];
    const float* ffn_b3 = (const float*)d_in[24];
    const float* out_W  = (const float*)d_in[25];
    const float* out_b  = (const float*)d_in[26];

    float* wsf = (float*)d_ws;
    unsigned short* xwb   = (unsigned short*)(wsf);              // (B*T,192) bf16
    unsigned short* seqhb = (unsigned short*)(wsf + 19660800);   // (B,T,64) bf16
    float* scores = wsf + 26214400;            // B*T
    float* target = wsf + 26419200;            // B*64
    float* other  = wsf + 26484736;            // B*36
    float* finals = wsf + 26521600;            // B*64
    float* f1     = wsf + 26587136;            // B*256
    float* f2     = wsf + 26849280;            // B*128
    float* f3     = wsf + 26980352;            // B*64
    float* st1    = wsf + 27045888;            // 512
    float* st2    = wsf + 27046400;            // 256
    float* st3    = wsf + 27046656;            // 128

    float* dout = (float*)d_out;
    const int Mtiles = (BB * TT) / 16;  // 12800

    k_prep<<<BB, 64, 0, stream>>>(dense, sparse, item_idx, item_table, other_tab, target, other);

    // xw1 = gather(item_table, seq_idx) @ gru_W + gru_b  (bf16 MFMA)
    k_xw<1><<<800, 256, 0, stream>>>(seq_idx, item_table, nullptr, gru_W, gru_b, hist_len, xwb, Mtiles, 3200);

    // GRU1 recurrence -> seq_h bf16 (B,T,64)   [16 rows/wave MFMA scan, asm-batched]
    k_scanU<0><<<BB / 16, 64, 0, stream>>>(xwb, gru_U, hist_len, scores, seqhb, finals);

    // attention MLP (MFMA) + fused softmax -> scores
    k_att<<<BB, 256, 0, stream>>>(target, seqhb, att_W1, att_b1, att_W2, att_b2,
                                  att_W3, att_b3, hist_len, scores);

    // xw2 = seq_h @ aug_W + aug_b  (bf16 MFMA)
    k_xw<0><<<800, 256, 0, stream>>>(nullptr, nullptr, seqhb, aug_W, aug_b, hist_len, xwb, Mtiles, 3200);

    // AUGRU recurrence -> finals f32 (B,64)
    k_scanU<1><<<BB / 16, 64, 0, stream>>>(xwb, aug_U, hist_len, scores, nullptr, finals);

    k_fc1<<<BB, 256, 0, stream>>>(finals, target, other, ffn_W1, ffn_b1, f1);
    k_stats<256><<<256, 256, 0, stream>>>(f1, st1);
    k_fc2<<<BB, 256, 0, stream>>>(f1, st1, ffn_W2, ffn_b2, f2);
    k_stats<128><<<128, 256, 0, stream>>>(f2, st2);
    k_fc3<<<BB, 128, 0, stream>>>(f2, st2, ffn_W3, ffn_b3, f3);
    k_stats<64><<<64, 256, 0, stream>>>(f3, st3);
    k_out<<<BB, 64, 0, stream>>>(f3, st3, out_W, out_b, dout);
}

// Round 19
// 404.072 us; speedup vs baseline: 2.5162x; 2.5087x over previous
//
#include <hip/hip_runtime.h>

#define BB 1024
#define TT 200

typedef __attribute__((ext_vector_type(8))) short short8;
typedef __attribute__((ext_vector_type(2))) short short2v;
typedef __attribute__((ext_vector_type(4))) float f32x4;

__device__ __forceinline__ float sigmoidf_(float x) { return __fdividef(1.0f, 1.0f + __expf(-x)); }
__device__ __forceinline__ float tanh_fast(float x) {
    x = fminf(15.f, fmaxf(-15.f, x));
    float e = __expf(-2.f * x);
    return __fdividef(1.f - e, 1.f + e);
}
__device__ __forceinline__ float dicef_(float x, float m, float v) {
    return x * sigmoidf_((x - m) * rsqrtf(v + 1e-9f));
}
__device__ __forceinline__ unsigned short f2bf(float f) {
    unsigned u = __float_as_uint(f);
    unsigned r = u + 0x7fffu + ((u >> 16) & 1u);
    return (unsigned short)(r >> 16);
}
__device__ __forceinline__ float bf2f(unsigned short h) {
    return __uint_as_float(((unsigned)h) << 16);
}
__device__ __forceinline__ unsigned cvt_pk_bf16(float lo, float hi) {
    unsigned r;
    asm("v_cvt_pk_bf16_f32 %0, %1, %2" : "=v"(r) : "v"(lo), "v"(hi));
    return r;
}
union U8 { short8 s8; unsigned u[4]; };

// dot of two bf16 pairs accumulating into f32
#if __has_builtin(__builtin_amdgcn_fdot2_f32_bf16)
__device__ __forceinline__ float dot2bf(unsigned h2, unsigned u2, float c) {
    union { unsigned u; short2v s; } A, B;
    A.u = h2; B.u = u2;
    return __builtin_amdgcn_fdot2_f32_bf16(A.s, B.s, c, false);
}
#else
__device__ __forceinline__ float dot2bf(unsigned h2, unsigned u2, float c) {
    float h0 = __uint_as_float(h2 << 16), h1 = __uint_as_float(h2 & 0xffff0000u);
    float u0 = __uint_as_float(u2 << 16), u1 = __uint_as_float(u2 & 0xffff0000u);
    return fmaf(h1, u1, fmaf(h0, u0, c));
}
#endif

// ---------------------------------------------------------------------------
// k_prep
// ---------------------------------------------------------------------------
__global__ void k_prep(const float* __restrict__ dense, const int* __restrict__ sparse,
                       const int* __restrict__ item_idx, const float* __restrict__ table,
                       const float* __restrict__ other_tables,
                       float* __restrict__ target, float* __restrict__ other) {
    int b = blockIdx.x, l = threadIdx.x;  // 64 threads
    target[b * 64 + l] = table[(size_t)item_idx[b] * 64 + l];
    if (l < 4) other[b * 36 + l] = dense[b * 4 + l];
    else if (l < 20) other[b * 36 + l] = other_tables[(size_t)sparse[b * 2 + 0] * 16 + (l - 4)];
    else if (l < 36) other[b * 36 + l] = other_tables[1000 * 16 + (size_t)sparse[b * 2 + 1] * 16 + (l - 20)];
}

// ---------------------------------------------------------------------------
// k_xw: XW = X @ W + bias, bf16 MFMA, masked-tile skip
// ---------------------------------------------------------------------------
template <int GATHER>
__global__ __launch_bounds__(256, 1) void k_xw(
    const int* __restrict__ idx, const float* __restrict__ tablef,
    const unsigned short* __restrict__ Abf,
    const float* __restrict__ W, const float* __restrict__ bias,
    const int* __restrict__ hist_len,
    unsigned short* __restrict__ out, int Mtiles, int tilestride)
{
    const int l = threadIdx.x & 63;
    const int wv = threadIdx.x >> 6;
    const int lg = l >> 4;
    const int li = l & 15;

    short8 bfr[12][2];
    float bn[12];
#pragma unroll
    for (int nt = 0; nt < 12; ++nt) {
        bn[nt] = bias[nt * 16 + li];
#pragma unroll
        for (int c = 0; c < 2; ++c) {
#pragma unroll
            for (int j = 0; j < 8; ++j) {
                int k = c * 32 + lg * 8 + j;
                bfr[nt][c][j] = (short)f2bf(W[k * 192 + nt * 16 + li]);
            }
        }
    }

    for (int tile = blockIdx.x * 4 + wv; tile < Mtiles; tile += tilestride) {
        long row = (long)tile * 16 + li;
        {
            int bb = (int)(row / TT);
            int tt = (int)(row - (long)bb * TT);
            int vld = (tt < hist_len[bb]) ? 1 : 0;
            if (__ballot(vld) == 0ull) continue;
        }

        short8 a[2];
        if (GATHER) {
            long id = idx[row];
            const float* tp = tablef + id * 64 + lg * 8;
#pragma unroll
            for (int c = 0; c < 2; ++c) {
                f32x4 v0 = *(const f32x4*)(tp + c * 32);
                f32x4 v1 = *(const f32x4*)(tp + c * 32 + 4);
#pragma unroll
                for (int j = 0; j < 4; ++j) {
                    a[c][j] = (short)f2bf(v0[j]);
                    a[c][4 + j] = (short)f2bf(v1[j]);
                }
            }
        } else {
#pragma unroll
            for (int c = 0; c < 2; ++c)
                a[c] = *(const short8*)(Abf + row * 64 + c * 32 + lg * 8);
        }

        f32x4 acc[12];
#pragma unroll
        for (int nt = 0; nt < 12; ++nt) acc[nt] = (f32x4){0.f, 0.f, 0.f, 0.f};
#pragma unroll
        for (int c = 0; c < 2; ++c)
#pragma unroll
            for (int nt = 0; nt < 12; ++nt)
                acc[nt] = __builtin_amdgcn_mfma_f32_16x16x32_bf16(a[c], bfr[nt][c], acc[nt], 0, 0, 0);

#pragma unroll
        for (int nt = 0; nt < 12; ++nt)
#pragma unroll
            for (int j = 0; j < 4; ++j) {
                long orow = (long)tile * 16 + lg * 4 + j;
                out[orow * 192 + nt * 16 + li] = f2bf(acc[nt][j] + bn[nt]);
            }
    }
}

// ---------------------------------------------------------------------------
// k_scan11: recurrent h@U, ONE WAVE per batch row, zero barriers.
// U re-read from LDS each step (proven best structure) + depth-4 software-
// pipelined xw prefetch with named slots. This sits at the measured
// structural floor: ~1800cy/step = 4 waves/CU sharing the LDS pipe at
// ~24 b128-reads/step/wave (b128 ~12cy) + exposed latency; register
// residency for U is compiler-unreachable (r3-r10), MFMA scan is
// latency/spill-bound at 1 wave/CU (r5, r17, r18).
// ---------------------------------------------------------------------------
template <int AUG>
__global__ __launch_bounds__(64, 1) void k_scan11(
    const unsigned short* __restrict__ xw,   // (B*T,192) bf16
    const float* __restrict__ U,             // (64,192)
    const int* __restrict__ hist_len,
    const float* __restrict__ scores,        // (B,T)
    unsigned short* __restrict__ hout,       // (B,T,64) bf16 (GRU1)
    float* __restrict__ hfinal)              // (B,64) f32 (AUGRU)
{
    __shared__ unsigned Ul[64 * 96];         // 24 KB bf16-pair weight image
    __shared__ unsigned hb[32];              // 64 bf16 h values as 32 pairs
    const int l = threadIdx.x;
    const int b = blockIdx.x;
    const int len = hist_len[b];
    const unsigned sw = ((unsigned)l & 7u) << 2;  // uint-index XOR (16B chunks)

    unsigned* rowp = Ul + l * 96;
    for (int kk = 0; kk < 32; ++kk) {
        unsigned pz = cvt_pk_bf16(U[(2 * kk) * 192 + l],       U[(2 * kk + 1) * 192 + l]);
        unsigned pr = cvt_pk_bf16(U[(2 * kk) * 192 + 64 + l],  U[(2 * kk + 1) * 192 + 64 + l]);
        unsigned ph = cvt_pk_bf16(U[(2 * kk) * 192 + 128 + l], U[(2 * kk + 1) * 192 + 128 + l]);
        rowp[(kk ^ sw)]      = pz;
        rowp[32 + (kk ^ sw)] = pr;
        rowp[64 + (kk ^ sw)] = ph;
    }

    const unsigned short* xwr = xw + (size_t)b * TT * 192;
    const float* scr = scores + (size_t)b * TT;
    unsigned short* hor = hout + (size_t)b * TT * 64;

    unsigned short* hbs = (unsigned short*)hb;
    float h = 0.f;
    hbs[l] = 0;   // bf16 zero

    const uint4* H4 = (const uint4*)hb;

    // one GRU/AUGRU step consuming prefetched xw slot values
    auto step = [&](unsigned short cz, unsigned short cr, unsigned short ch,
                    float cs, int t) {
        float az0 = 0.f, az1 = 0.f, ar0 = 0.f, ar1 = 0.f, ah0 = 0.f, ah1 = 0.f;
#pragma unroll
        for (int q = 0; q < 8; ++q) {
            uint4 hq = H4[q];
            uint4 uz = *(const uint4*)(rowp + ((4 * q) ^ sw));
            uint4 ur = *(const uint4*)(rowp + 32 + ((4 * q) ^ sw));
            uint4 uh = *(const uint4*)(rowp + 64 + ((4 * q) ^ sw));
            az0 = dot2bf(hq.x, uz.x, az0);
            ar0 = dot2bf(hq.x, ur.x, ar0);
            ah0 = dot2bf(hq.x, uh.x, ah0);
            az1 = dot2bf(hq.y, uz.y, az1);
            ar1 = dot2bf(hq.y, ur.y, ar1);
            ah1 = dot2bf(hq.y, uh.y, ah1);
            az0 = dot2bf(hq.z, uz.z, az0);
            ar0 = dot2bf(hq.z, ur.z, ar0);
            ah0 = dot2bf(hq.z, uh.z, ah0);
            az1 = dot2bf(hq.w, uz.w, az1);
            ar1 = dot2bf(hq.w, ur.w, ar1);
            ah1 = dot2bf(hq.w, uh.w, ah1);
        }
        float azf = az0 + az1, arf = ar0 + ar1, ahf = ah0 + ah1;

        float zg = sigmoidf_(bf2f(cz) + azf);
        if (AUG) zg *= cs;
        float rg = sigmoidf_(bf2f(cr) + arf);
        float hv = tanh_fast(bf2f(ch) + rg * ahf);
        h = (1.f - zg) * h + zg * hv;

        const unsigned short hbf = f2bf(h);
        hbs[l] = hbf;  // may-alias this step's h reads -> ordered; in-order DS pipe
        if (!AUG) hor[(size_t)t * 64 + l] = hbf;
    };

#define DECL_SLOT(i) unsigned short pz##i = 0, pr##i = 0, ph##i = 0; float ps##i = 0.f;
#define LOAD_SLOT(i, tt) { const unsigned short* p_ = xwr + (size_t)(tt) * 192; \
        pz##i = p_[l]; pr##i = p_[64 + l]; ph##i = p_[128 + l]; \
        if (AUG) ps##i = scr[(tt)]; }

    DECL_SLOT(0) DECL_SLOT(1) DECL_SLOT(2) DECL_SLOT(3)
    if (len > 0) LOAD_SLOT(0, 0)
    if (len > 1) LOAD_SLOT(1, 1)
    if (len > 2) LOAD_SLOT(2, 2)
    if (len > 3) LOAD_SLOT(3, 3)

    const int lenm = len & ~3;
    int t = 0;
    for (; t < lenm; t += 4) {
        {
            const unsigned short cz = pz0, cr = pr0, ch = ph0; const float cs = ps0;
            if (t + 4 < len) LOAD_SLOT(0, t + 4)
            step(cz, cr, ch, cs, t);
        }
        {
            const unsigned short cz = pz1, cr = pr1, ch = ph1; const float cs = ps1;
            if (t + 5 < len) LOAD_SLOT(1, t + 5)
            step(cz, cr, ch, cs, t + 1);
        }
        {
            const unsigned short cz = pz2, cr = pr2, ch = ph2; const float cs = ps2;
            if (t + 6 < len) LOAD_SLOT(2, t + 6)
            step(cz, cr, ch, cs, t + 2);
        }
        {
            const unsigned short cz = pz3, cr = pr3, ch = ph3; const float cs = ps3;
            if (t + 7 < len) LOAD_SLOT(3, t + 7)
            step(cz, cr, ch, cs, t + 3);
        }
    }
    // tail: 0..3 steps, slots 0..2 already loaded (lenm % 4 == 0)
    if (t + 0 < len) step(pz0, pr0, ph0, ps0, t + 0);
    if (t + 1 < len) step(pz1, pr1, ph1, ps1, t + 1);
    if (t + 2 < len) step(pz2, pr2, ph2, ps2, t + 2);

#undef DECL_SLOT
#undef LOAD_SLOT

    if (AUG) {
        hfinal[(size_t)b * 64 + l] = h;
    } else {
        const unsigned short fro = f2bf(h);
        for (int tt = len; tt < TT; ++tt) hor[(size_t)tt * 64 + l] = fro;
    }
}

// ---------------------------------------------------------------------------
// k_att: bf16 MFMA attention + fused softmax, len-clipped tiles
// ---------------------------------------------------------------------------
__global__ __launch_bounds__(256, 2) void k_att(
    const float* __restrict__ target, const unsigned short* __restrict__ seq_hb,
    const float* __restrict__ W1, const float* __restrict__ b1,
    const float* __restrict__ W2, const float* __restrict__ b2,
    const float* __restrict__ W3, const float* __restrict__ b3,
    const int* __restrict__ hist_len, float* __restrict__ scores)
{
    __shared__ unsigned short W1f[8 * 4 * 64 * 8];  // frag layout, 32 KB
    __shared__ float a1s[4][16][68];
    __shared__ float logit_lds[208];
    __shared__ float red[8];

    const int tid = threadIdx.x;
    const int wv = tid >> 6, l = tid & 63;
    const int lg = l >> 4, li = l & 15;
    const int b = blockIdx.x;
    const int len = hist_len[b];

    if (tid < 208) logit_lds[tid] = -1e9f;
    for (int i = tid; i < 8 * 4 * 64 * 8; i += 256) {
        int j = i & 7, ll = (i >> 3) & 63, nt = (i >> 9) & 3, c = i >> 11;
        int k = c * 32 + (ll >> 4) * 8 + j;
        int col = nt * 16 + (ll & 15);
        W1f[i] = f2bf(W1[k * 64 + col]);
    }
    __syncthreads();

    short8 w1r[8][4];
    const short8* wf = (const short8*)W1f;
#pragma unroll
    for (int c = 0; c < 8; ++c)
#pragma unroll
        for (int nt = 0; nt < 4; ++nt)
            w1r[c][nt] = wf[(c * 4 + nt) * 64 + l];

    short8 w2r[2];
#pragma unroll
    for (int c = 0; c < 2; ++c) {
        U8 t8;
#pragma unroll
        for (int m = 0; m < 4; ++m) {
            int k0 = c * 32 + lg * 8 + 2 * m;
            t8.u[m] = cvt_pk_bf16(W2[k0 * 16 + li], W2[(k0 + 1) * 16 + li]);
        }
        w2r[c] = t8.s8;
    }

    float b1v[4];
#pragma unroll
    for (int nt = 0; nt < 4; ++nt) b1v[nt] = b1[nt * 16 + li];
    const float b2v = b2[li];
    const float w3v = W3[li];
    const float b3r = b3[0];

    const float* qp = target + (size_t)b * 64;
    float qf_lo[8], qf_hi[8];
#pragma unroll
    for (int j = 0; j < 8; ++j) { qf_lo[j] = qp[lg * 8 + j]; qf_hi[j] = qp[32 + lg * 8 + j]; }
    U8 q8l, q8h;
#pragma unroll
    for (int m = 0; m < 4; ++m) {
        q8l.u[m] = cvt_pk_bf16(qf_lo[2 * m], qf_lo[2 * m + 1]);
        q8h.u[m] = cvt_pk_bf16(qf_hi[2 * m], qf_hi[2 * m + 1]);
    }

    for (int mt = wv; mt * 16 < len; mt += 4) {
        const int t = mt * 16 + li;
        const int tld = (t < TT) ? t : TT - 1;
        const unsigned short* hp = seq_hb + ((size_t)b * TT + tld) * 64 + lg * 8;
        short8 h8l = *(const short8*)hp;
        short8 h8h = *(const short8*)(hp + 32);

        U8 d8l, d8h, m8l, m8h;
#pragma unroll
        for (int m = 0; m < 4; ++m) {
            float h0, h1, d0, d1, p0, p1;
            h0 = bf2f((unsigned short)h8l[2 * m]); h1 = bf2f((unsigned short)h8l[2 * m + 1]);
            d0 = qf_lo[2 * m] - h0; d1 = qf_lo[2 * m + 1] - h1;
            p0 = qf_lo[2 * m] * h0; p1 = qf_lo[2 * m + 1] * h1;
            d8l.u[m] = cvt_pk_bf16(d0, d1);
            m8l.u[m] = cvt_pk_bf16(p0, p1);
            h0 = bf2f((unsigned short)h8h[2 * m]); h1 = bf2f((unsigned short)h8h[2 * m + 1]);
            d0 = qf_hi[2 * m] - h0; d1 = qf_hi[2 * m + 1] - h1;
            p0 = qf_hi[2 * m] * h0; p1 = qf_hi[2 * m + 1] * h1;
            d8h.u[m] = cvt_pk_bf16(d0, d1);
            m8h.u[m] = cvt_pk_bf16(p0, p1);
        }

        f32x4 acc[4];
#pragma unroll
        for (int nt = 0; nt < 4; ++nt) acc[nt] = (f32x4){0.f, 0.f, 0.f, 0.f};
#pragma unroll
        for (int nt = 0; nt < 4; ++nt) {
            acc[nt] = __builtin_amdgcn_mfma_f32_16x16x32_bf16(q8l.s8, w1r[0][nt], acc[nt], 0, 0, 0);
            acc[nt] = __builtin_amdgcn_mfma_f32_16x16x32_bf16(q8h.s8, w1r[1][nt], acc[nt], 0, 0, 0);
            acc[nt] = __builtin_amdgcn_mfma_f32_16x16x32_bf16(h8l,    w1r[2][nt], acc[nt], 0, 0, 0);
            acc[nt] = __builtin_amdgcn_mfma_f32_16x16x32_bf16(h8h,    w1r[3][nt], acc[nt], 0, 0, 0);
            acc[nt] = __builtin_amdgcn_mfma_f32_16x16x32_bf16(d8l.s8, w1r[4][nt], acc[nt], 0, 0, 0);
            acc[nt] = __builtin_amdgcn_mfma_f32_16x16x32_bf16(d8h.s8, w1r[5][nt], acc[nt], 0, 0, 0);
            acc[nt] = __builtin_amdgcn_mfma_f32_16x16x32_bf16(m8l.s8, w1r[6][nt], acc[nt], 0, 0, 0);
            acc[nt] = __builtin_amdgcn_mfma_f32_16x16x32_bf16(m8h.s8, w1r[7][nt], acc[nt], 0, 0, 0);
        }

#pragma unroll
        for (int nt = 0; nt < 4; ++nt)
#pragma unroll
            for (int jj = 0; jj < 4; ++jj) {
                float v = acc[nt][jj] + b1v[nt];
                a1s[wv][lg * 4 + jj][nt * 16 + li] = (v > 0.f) ? v : 0.25f * v;
            }

        const float* arow = &a1s[wv][li][0];
        f32x4 acc2 = (f32x4){0.f, 0.f, 0.f, 0.f};
#pragma unroll
        for (int c2 = 0; c2 < 2; ++c2) {
            f32x4 v0 = *(const f32x4*)(arow + c2 * 32 + lg * 8);
            f32x4 v1 = *(const f32x4*)(arow + c2 * 32 + lg * 8 + 4);
            U8 a2f;
            a2f.u[0] = cvt_pk_bf16(v0[0], v0[1]);
            a2f.u[1] = cvt_pk_bf16(v0[2], v0[3]);
            a2f.u[2] = cvt_pk_bf16(v1[0], v1[1]);
            a2f.u[3] = cvt_pk_bf16(v1[2], v1[3]);
            acc2 = __builtin_amdgcn_mfma_f32_16x16x32_bf16(a2f.s8, w2r[c2], acc2, 0, 0, 0);
        }

#pragma unroll
        for (int jj = 0; jj < 4; ++jj) {
            float a2 = acc2[jj] + b2v;
            a2 = (a2 > 0.f) ? a2 : 0.25f * a2;
            float part = a2 * w3v;
            part += __shfl_xor(part, 1);
            part += __shfl_xor(part, 2);
            part += __shfl_xor(part, 4);
            part += __shfl_xor(part, 8);
            int tt = mt * 16 + lg * 4 + jj;
            if (li == 0 && tt < TT)
                logit_lds[tt] = (tt < len) ? (part + b3r) : -1e9f;
        }
    }
    __syncthreads();

    float v = (tid < TT) ? logit_lds[tid] : -1e30f;
    float m = v;
#pragma unroll
    for (int s = 1; s < 64; s <<= 1) m = fmaxf(m, __shfl_xor(m, s));
    if (l == 0) red[wv] = m;
    __syncthreads();
    m = fmaxf(fmaxf(red[0], red[1]), fmaxf(red[2], red[3]));
    float e = (tid < TT) ? __expf(v - m) : 0.f;
    float sum = e;
#pragma unroll
    for (int s = 1; s < 64; s <<= 1) sum += __shfl_xor(sum, s);
    if (l == 0) red[4 + wv] = sum;
    __syncthreads();
    float inv = __fdividef(1.f, red[4] + red[5] + red[6] + red[7]);
    if (tid < TT) scores[(size_t)b * TT + tid] = e * inv;
}

// ---------------------------------------------------------------------------
// FFN chain (tiny)
// ---------------------------------------------------------------------------
__global__ __launch_bounds__(256) void k_fc1(const float* __restrict__ fin,
                                             const float* __restrict__ tgt,
                                             const float* __restrict__ oth,
                                             const float* __restrict__ Wt,
                                             const float* __restrict__ bvec,
                                             float* __restrict__ fout) {
    __shared__ float z0[164];
    int b = blockIdx.x, tid = threadIdx.x;
    if (tid < 64) z0[tid] = fin[b * 64 + tid];
    else if (tid < 128) z0[tid] = tgt[b * 64 + tid - 64];
    else if (tid < 164) z0[tid] = oth[b * 36 + tid - 128];
    __syncthreads();
    float acc = bvec[tid];
#pragma unroll 4
    for (int k = 0; k < 164; ++k) acc += z0[k] * Wt[k * 256 + tid];
    fout[(size_t)b * 256 + tid] = acc;
}

template <int F>
__global__ __launch_bounds__(256) void k_stats(const float* __restrict__ x, float* __restrict__ stat) {
    int c = blockIdx.x, tid = threadIdx.x;
    float s = 0.f, sq = 0.f;
    for (int i = tid; i < BB; i += 256) {
        float v = x[(size_t)i * F + c];
        s += v; sq += v * v;
    }
#pragma unroll
    for (int m = 1; m < 64; m <<= 1) { s += __shfl_xor(s, m); sq += __shfl_xor(sq, m); }
    __shared__ float rs[4], rq[4];
    if ((tid & 63) == 0) { rs[tid >> 6] = s; rq[tid >> 6] = sq; }
    __syncthreads();
    if (tid == 0) {
        float S = rs[0] + rs[1] + rs[2] + rs[3];
        float Q = rq[0] + rq[1] + rq[2] + rq[3];
        float mean = S * (1.f / BB);
        float var = Q * (1.f / BB) - mean * mean;
        stat[c] = mean;
        stat[F + c] = var;
    }
}

__global__ __launch_bounds__(256) void k_fc2(const float* __restrict__ f1,
                                             const float* __restrict__ st1,
                                             const float* __restrict__ Wt,
                                             const float* __restrict__ bvec,
                                             float* __restrict__ f2) {
    __shared__ float z[256];
    int b = blockIdx.x, tid = threadIdx.x;
    float x = f1[(size_t)b * 256 + tid];
    z[tid] = dicef_(x, st1[tid], st1[256 + tid]);
    __syncthreads();
    if (tid < 128) {
        float acc = bvec[tid];
#pragma unroll 4
        for (int k = 0; k < 256; ++k) acc += z[k] * Wt[k * 128 + tid];
        f2[(size_t)b * 128 + tid] = acc;
    }
}

__global__ __launch_bounds__(128) void k_fc3(const float* __restrict__ f2,
                                             const float* __restrict__ st2,
                                             const float* __restrict__ Wt,
                                             const float* __restrict__ bvec,
                                             float* __restrict__ f3) {
    __shared__ float z[128];
    int b = blockIdx.x, tid = threadIdx.x;
    float x = f2[(size_t)b * 128 + tid];
    z[tid] = dicef_(x, st2[tid], st2[128 + tid]);
    __syncthreads();
    if (tid < 64) {
        float acc = bvec[tid];
#pragma unroll 4
        for (int k = 0; k < 128; ++k) acc += z[k] * Wt[k * 64 + tid];
        f3[(size_t)b * 64 + tid] = acc;
    }
}

__global__ void k_out(const float* __restrict__ f3, const float* __restrict__ st3,
                      const float* __restrict__ outW, const float* __restrict__ outb,
                      float* __restrict__ out) {
    int b = blockIdx.x, l = threadIdx.x;  // 64 threads
    float x = f3[(size_t)b * 64 + l];
    float z = dicef_(x, st3[l], st3[64 + l]);
    float p = z * outW[l];
#pragma unroll
    for (int m = 1; m < 64; m <<= 1) p += __shfl_xor(p, m);
    if (l == 0) out[b] = sigmoidf_(p + outb[0]);
}

// ---------------------------------------------------------------------------
extern "C" void kernel_launch(void* const* d_in, const int* in_sizes, int n_in,
                              void* d_out, int out_size, void* d_ws, size_t ws_size,
                              hipStream_t stream) {
    const float* dense      = (const float*)d_in[0];
    const int*   sparse     = (const int*)d_in[1];
    const int*   seq_idx    = (const int*)d_in[2];
    const int*   item_idx   = (const int*)d_in[3];
    const int*   hist_len   = (const int*)d_in[4];
    const float* item_table = (const float*)d_in[5];
    const float* other_tab  = (const float*)d_in[6];
    const float* gru_W = (const float*)d_in[7];
    const float* gru_U = (const float*)d_in[8];
    const float* gru_b = (const float*)d_in[9];
    const float* aug_W = (const float*)d_in[10];
    const float* aug_U = (const float*)d_in[11];
    const float* aug_b = (const float*)d_in[12];
    const float* att_W1 = (const float*)d_in[13];
    const float* att_b1 = (const float*)d_in[14];
    const float* att_W2 = (const float*)d_in[15];
    const float* att_b2 = (const float*)d_in[16];
    const float* att_W3 = (const float*)d_in[17];
    const float* att_b3 = (const float*)d_in[18];
    const float* ffn_W1 = (const float*)d_in[19];
    const float* ffn_b1 = (const float*)d_in[20];
    const float* ffn_W2 = (const float*)d_in[21];
    const float* ffn_b2 = (const float*)d_in[22];
    const float* ffn_W3 = (const float*)d_in[23];
    const float* ffn_b3 = (const float*)d_in[24];
    const float* out_W  = (const float*)d_in[25];
    const float* out_b  = (const float*)d_in[26];

    float* wsf = (float*)d_ws;
    unsigned short* xwb   = (unsigned short*)(wsf);              // (B*T,192) bf16
    unsigned short* seqhb = (unsigned short*)(wsf + 19660800);   // (B,T,64) bf16
    float* scores = wsf + 26214400;            // B*T
    float* target = wsf + 26419200;            // B*64
    float* other  = wsf + 26484736;            // B*36
    float* finals = wsf + 26521600;            // B*64
    float* f1     = wsf + 26587136;            // B*256
    float* f2     = wsf + 26849280;            // B*128
    float* f3     = wsf + 26980352;            // B*64
    float* st1    = wsf + 27045888;            // 512
    float* st2    = wsf + 27046400;            // 256
    float* st3    = wsf + 27046656;            // 128

    float* dout = (float*)d_out;
    const int Mtiles = (BB * TT) / 16;  // 12800

    k_prep<<<BB, 64, 0, stream>>>(dense, sparse, item_idx, item_table, other_tab, target, other);

    // xw1 = gather(item_table, seq_idx) @ gru_W + gru_b  (bf16 MFMA, masked tiles skipped)
    k_xw<1><<<800, 256, 0, stream>>>(seq_idx, item_table, nullptr, gru_W, gru_b, hist_len, xwb, Mtiles, 3200);

    // GRU1 recurrence -> seq_h bf16 (B,T,64)   [1 wave/row, LDS U, depth-4 prefetch]
    k_scan11<0><<<BB, 64, 0, stream>>>(xwb, gru_U, hist_len, scores, seqhb, finals);

    // attention MLP (MFMA) + fused softmax -> scores
    k_att<<<BB, 256, 0, stream>>>(target, seqhb, att_W1, att_b1, att_W2, att_b2,
                                  att_W3, att_b3, hist_len, scores);

    // xw2 = seq_h @ aug_W + aug_b  (bf16 MFMA, masked tiles skipped)
    k_xw<0><<<800, 256, 0, stream>>>(nullptr, nullptr, seqhb, aug_W, aug_b, hist_len, xwb, Mtiles, 3200);

    // AUGRU recurrence -> finals f32 (B,64)
    k_scan11<1><<<BB, 64, 0, stream>>>(xwb, aug_U, hist_len, scores, seqhb, finals);

    k_fc1<<<BB, 256, 0, stream>>>(finals, target, other, ffn_W1, ffn_b1, f1);
    k_stats<256><<<256, 256, 0, stream>>>(f1, st1);
    k_fc2<<<BB, 256, 0, stream>>>(f1, st1, ffn_W2, ffn_b2, f2);
    k_stats<128><<<128, 256, 0, stream>>>(f2, st2);
    k_fc3<<<BB, 128, 0, stream>>>(f2, st2, ffn_W3, ffn_b3, f3);
    k_stats<64><<<64, 256, 0, stream>>>(f3, st3);
    k_out<<<BB, 64, 0, stream>>>(f3, st3, out_W, out_b, dout);
}